// Round 2
// baseline (416.524 us; speedup 1.0000x reference)
//
#include <hip/hip_runtime.h>
#include <float.h>

#define DIM      512
#define NCLS     21
#define MARGIN_V 5.0f
#define ROWS_PB  64            // rows per block; lane t of every wave owns row t
#define NWAVES   4             // waves per block, each owns a 128-float depth slice
#define WSLICE   (DIM / NWAVES)   // 128
#define DC       32            // floats staged per stage
#define NSTAGE   (WSLICE / DC)    // 4
#define REDS     23            // padded stride for cross-wave reduce (odd vs 32 banks)

// Kernel 1: halfc2[c] = 0.5 * ||centers[c]||^2  -> d_ws
__global__ __launch_bounds__(64)
void center_norm_kernel(const float* __restrict__ centers,
                        float* __restrict__ halfc2) {
    const int c = blockIdx.x;
    const int t = threadIdx.x;
    float s = 0.f;
#pragma unroll
    for (int i = 0; i < DIM / 64; ++i) {
        float v = centers[c * DIM + i * 64 + t];
        s = fmaf(v, v, s);
    }
#pragma unroll
    for (int off = 32; off > 0; off >>= 1)
        s += __shfl_down(s, off, 64);
    if (t == 0) halfc2[c] = 0.5f * s;
}

// Kernel 2: 64 rows/block, depth split across 4 waves, no barriers in K-loop.
__global__ __launch_bounds__(256, 4)
void tcl_main_kernel(const float* __restrict__ feat,
                     const float* __restrict__ centers,
                     const int* __restrict__ labels,
                     const float* __restrict__ halfc2,
                     float* __restrict__ out) {
    // 4 waves x (64 rows x 32 floats) = 8192 floats = 32 KB.
    // Reused (after barrier) as red[4][64][REDS] = 5888 floats for the reduce.
    __shared__ float smem[NWAVES * ROWS_PB * DC];

    const int tid  = threadIdx.x;
    const int w    = tid >> 6;      // wave id 0..3
    const int t    = tid & 63;      // lane id == row within block
    const int row0 = blockIdx.x * ROWS_PB;

    // wave-private tile, XOR-swizzled float4 layout:
    //   slot = r*8 + (j4 ^ (r&7)) holds row r, float4-column j4
    float4* tile4 = reinterpret_cast<float4*>(smem + w * (ROWS_PB * DC));

    // global base: row0, plus this wave's depth slice (in float4 units)
    const float4* fb = reinterpret_cast<const float4*>(feat)
                     + (size_t)row0 * (DIM / 4) + w * (WSLICE / 4);

    float acc[NCLS];
#pragma unroll
    for (int c = 0; c < NCLS; ++c) acc[c] = 0.f;

    const int xr = t & 7;   // readback xor key for lane t (row t)

#pragma unroll 1
    for (int s = 0; s < NSTAGE; ++s) {
        // Stage in 64 rows x 8 float4. Lane's k-th store goes to slot k*64+t
        // (contiguous b128 writes); it loads the global float4 that belongs
        // in that swizzled slot. Groups of 8 lanes cover the same 128-B
        // segment (permuted) -> fully coalesced.
        float4 v[8];
#pragma unroll
        for (int k = 0; k < 8; ++k) {
            int slot = k * 64 + t;
            int r    = slot >> 3;
            int j4   = (slot & 7) ^ (r & 7);
            v[k] = fb[(size_t)r * (DIM / 4) + s * (DC / 4) + j4];
        }
#pragma unroll
        for (int k = 0; k < 8; ++k)
            tile4[k * 64 + t] = v[k];

        const int dbase = w * WSLICE + s * DC;
#pragma unroll
        for (int jj4 = 0; jj4 < 8; ++jj4) {
            float4 f = tile4[t * 8 + (jj4 ^ xr)];   // row t, col jj4; conflict-free
            const int d = dbase + jj4 * 4;
#pragma unroll
            for (int c = 0; c < NCLS; ++c) {
                const float* cp = &centers[c * DIM + d];   // wave-uniform -> s_load
                acc[c] = fmaf(f.x, cp[0],
                          fmaf(f.y, cp[1],
                           fmaf(f.z, cp[2],
                            fmaf(f.w, cp[3], acc[c]))));
            }
        }
    }

    // cross-wave reduce: overlay smem with red[w][t][c], stride REDS=23
    __syncthreads();                 // all waves done reading their tiles
#pragma unroll
    for (int c = 0; c < NCLS; ++c)
        smem[(w * ROWS_PB + t) * REDS + c] = acc[c];
    __syncthreads();

    if (w == 0) {
        const int lab = labels[row0 + t];
        float pos = 0.f, neg = FLT_MAX;
#pragma unroll
        for (int c = 0; c < NCLS; ++c) {
            float dot = smem[(0 * ROWS_PB + t) * REDS + c]
                      + smem[(1 * ROWS_PB + t) * REDS + c]
                      + smem[(2 * ROWS_PB + t) * REDS + c]
                      + smem[(3 * ROWS_PB + t) * REDS + c];
            float e = halfc2[c] - dot;               // ||f||^2 cancels in pos-neg
            pos = (c == lab) ? e : pos;
            neg = (c == lab) ? neg : fminf(neg, e);
        }
        float vv = fmaxf(pos + MARGIN_V - neg, 0.f);
#pragma unroll
        for (int off = 32; off > 0; off >>= 1)
            vv += __shfl_down(vv, off, 64);
        if (t == 0) atomicAdd(out, vv * (1.0f / 65536.f));
    }
}

extern "C" void kernel_launch(void* const* d_in, const int* in_sizes, int n_in,
                              void* d_out, int out_size, void* d_ws, size_t ws_size,
                              hipStream_t stream) {
    const float* feat    = (const float*)d_in[0];   // (65536, 512) fp32
    const float* centers = (const float*)d_in[1];   // (21, 512) fp32
    const int*   labels  = (const int*)d_in[2];     // (65536,)
    float* out    = (float*)d_out;                  // scalar loss
    float* halfc2 = (float*)d_ws;                   // 21 floats scratch

    hipMemsetAsync(d_out, 0, (size_t)out_size * sizeof(float), stream);
    center_norm_kernel<<<NCLS, 64, 0, stream>>>(centers, halfc2);

    const int nblocks = 65536 / ROWS_PB;            // 1024 blocks x 256 threads
    tcl_main_kernel<<<nblocks, 256, 0, stream>>>(feat, centers, labels, halfc2, out);
}

// Round 3
// 393.025 us; speedup vs baseline: 1.0598x; 1.0598x over previous
//
#include <hip/hip_runtime.h>
#include <float.h>
#include <stdint.h>

#define DIM      512
#define NCLS     21
#define MARGIN_V 5.0f
#define ROWS_PB  64              // rows per block; lane t of every wave owns row t
#define NWAVES   4               // waves per block, each owns a 128-float depth slice
#define WSLICE   (DIM / NWAVES)  // 128
#define DC       32              // floats staged per stage per wave
#define NSTAGE   (WSLICE / DC)   // 4
#define REDS     23              // padded stride for cross-wave reduce

typedef __attribute__((address_space(3))) uint32_t       lds_u32_t;
typedef const __attribute__((address_space(1))) uint32_t glb_u32_t;

// Kernel 1: halfc2[c] = 0.5*||centers[c]||^2 -> d_ws ; block 0 also zeroes d_out
__global__ __launch_bounds__(64)
void center_norm_kernel(const float* __restrict__ centers,
                        float* __restrict__ halfc2,
                        float* __restrict__ out) {
    const int c = blockIdx.x;
    const int t = threadIdx.x;
    if (c == 0 && t == 0) out[0] = 0.f;     // replaces hipMemsetAsync (same-stream order)
    float s = 0.f;
#pragma unroll
    for (int i = 0; i < DIM / 64; ++i) {
        float v = centers[c * DIM + i * 64 + t];
        s = fmaf(v, v, s);
    }
#pragma unroll
    for (int off = 32; off > 0; off >>= 1)
        s += __shfl_down(s, off, 64);
    if (t == 0) halfc2[c] = 0.5f * s;
}

// Kernel 2: 64 rows/block, depth split across 4 waves; global->LDS DMA staging
// (no staging VGPRs -> no spill, the round-2 killer).
__global__ __launch_bounds__(256, 4)
void tcl_main_kernel(const float* __restrict__ feat,
                     const float* __restrict__ centers,
                     const int* __restrict__ labels,
                     const float* __restrict__ halfc2,
                     float* __restrict__ out) {
    // 4 waves x (64 rows x 32 floats) = 32 KB; reused for the cross-wave reduce.
    __shared__ float smem[NWAVES * ROWS_PB * DC];

    const int tid  = threadIdx.x;
    const int w    = tid >> 6;      // wave id 0..3 (depth slice)
    const int t    = tid & 63;      // lane id == row within block
    const int row0 = blockIdx.x * ROWS_PB;

    // wave-private tile in float4 units; XOR-swizzled:
    //   slot = r*8 + (j4 ^ (r&7)) holds row r, float4-col j4
    float4* tile4 = reinterpret_cast<float4*>(smem) + w * (ROWS_PB * DC / 4);

    const float4* fb = reinterpret_cast<const float4*>(feat)
                     + (size_t)row0 * (DIM / 4) + w * (WSLICE / 4);

    float acc[NCLS];
#pragma unroll
    for (int c = 0; c < NCLS; ++c) acc[c] = 0.f;

    const int xr = t & 7;           // readback xor key for lane t (row t)

#pragma unroll 1
    for (int s = 0; s < NSTAGE; ++s) {
        __syncthreads();            // prior stage fully consumed before DMA overwrites
        // 8 DMA issues: issue k deposits at LDS base (tile4+k*64) + lane*16,
        // i.e. slot k*64+t. Lane's global source is the float4 belonging in
        // that swizzled slot: r = slot>>3, j4 = (slot&7)^(r&7). Each 8-lane
        // group covers one row's 128 B (permuted) -> fully coalesced.
#pragma unroll
        for (int k = 0; k < 8; ++k) {
            int slot = k * 64 + t;
            int r    = slot >> 3;
            int j4   = (slot & 7) ^ (r & 7);
            const float4* gp = fb + (size_t)r * (DIM / 4) + s * (DC / 4) + j4;
            __builtin_amdgcn_global_load_lds((glb_u32_t*)gp,
                                             (lds_u32_t*)(tile4 + k * 64),
                                             16, 0, 0);
        }
        __syncthreads();            // DMA complete (barrier drains vmcnt)

        const int dbase = w * WSLICE + s * DC;
#pragma unroll
        for (int jj4 = 0; jj4 < 8; ++jj4) {
            float4 f = tile4[t * 8 + (jj4 ^ xr)];   // row t, col jj4; bank-balanced
            const int d = dbase + jj4 * 4;
#pragma unroll
            for (int c = 0; c < NCLS; ++c) {
                const float* cp = &centers[c * DIM + d];   // wave-uniform -> s_load
                acc[c] = fmaf(f.x, cp[0],
                          fmaf(f.y, cp[1],
                           fmaf(f.z, cp[2],
                            fmaf(f.w, cp[3], acc[c]))));
            }
        }
    }

    // cross-wave reduce: overlay smem with red[w][t][c], stride REDS=23
    __syncthreads();
#pragma unroll
    for (int c = 0; c < NCLS; ++c)
        smem[(w * ROWS_PB + t) * REDS + c] = acc[c];
    __syncthreads();

    if (w == 0) {
        const int lab = labels[row0 + t];
        float pos = 0.f, neg = FLT_MAX;
#pragma unroll
        for (int c = 0; c < NCLS; ++c) {
            float dot = smem[(0 * ROWS_PB + t) * REDS + c]
                      + smem[(1 * ROWS_PB + t) * REDS + c]
                      + smem[(2 * ROWS_PB + t) * REDS + c]
                      + smem[(3 * ROWS_PB + t) * REDS + c];
            float e = halfc2[c] - dot;               // ||f||^2 cancels in pos-neg
            pos = (c == lab) ? e : pos;
            neg = (c == lab) ? neg : fminf(neg, e);
        }
        float vv = fmaxf(pos + MARGIN_V - neg, 0.f);
#pragma unroll
        for (int off = 32; off > 0; off >>= 1)
            vv += __shfl_down(vv, off, 64);
        if (t == 0) atomicAdd(out, vv * (1.0f / 65536.f));
    }
}

extern "C" void kernel_launch(void* const* d_in, const int* in_sizes, int n_in,
                              void* d_out, int out_size, void* d_ws, size_t ws_size,
                              hipStream_t stream) {
    const float* feat    = (const float*)d_in[0];   // (65536, 512) fp32
    const float* centers = (const float*)d_in[1];   // (21, 512) fp32
    const int*   labels  = (const int*)d_in[2];     // (65536,)
    float* out    = (float*)d_out;                  // scalar loss
    float* halfc2 = (float*)d_ws;                   // 21 floats scratch

    center_norm_kernel<<<NCLS, 64, 0, stream>>>(centers, halfc2, out);

    const int nblocks = 65536 / ROWS_PB;            // 1024 blocks x 256 threads
    tcl_main_kernel<<<nblocks, 256, 0, stream>>>(feat, centers, labels, halfc2, out);
}

// Round 4
// 276.822 us; speedup vs baseline: 1.5047x; 1.4198x over previous
//
#include <hip/hip_runtime.h>
#include <float.h>
#include <stdint.h>

#define DIM      512
#define NCLS     21
#define MARGIN_V 5.0f
#define ROWS_PB  64              // rows per block; lane t of every wave owns row t
#define NWAVES   4               // waves per block, each owns a 128-float depth slice
#define WSLICE   (DIM / NWAVES)  // 128
#define DC       32              // floats staged per stage per wave
#define NSTAGE   (WSLICE / DC)   // 4
#define REDS     23              // padded stride for cross-wave reduce

typedef __attribute__((address_space(3))) uint32_t       lds_u32_t;
typedef const __attribute__((address_space(1))) uint32_t glb_u32_t;

// Kernel 1: halfc2[c] = 0.5*||centers[c]||^2 -> d_ws ; block 0 also zeroes d_out
__global__ __launch_bounds__(64)
void center_norm_kernel(const float* __restrict__ centers,
                        float* __restrict__ halfc2,
                        float* __restrict__ out) {
    const int c = blockIdx.x;
    const int t = threadIdx.x;
    if (c == 0 && t == 0) out[0] = 0.f;     // same-stream order replaces memset
    float s = 0.f;
#pragma unroll
    for (int i = 0; i < DIM / 64; ++i) {
        float v = centers[c * DIM + i * 64 + t];
        s = fmaf(v, v, s);
    }
#pragma unroll
    for (int off = 32; off > 0; off >>= 1)
        s += __shfl_down(s, off, 64);
    if (t == 0) halfc2[c] = 0.5f * s;
}

// Kernel 2: 64 rows/block, depth split across 4 waves; global->LDS DMA staging.
// NOTE: no min-waves-per-EU hint — round 2/3's (256,4) pinned VGPR=64 and the
// compiler spilled ~500 MB of scratch instead of relaxing to 128. LDS
// (32 KB/block) caps occupancy at 5 blocks/CU regardless, so VGPR<=~100 is free.
__global__ __launch_bounds__(256)
void tcl_main_kernel(const float* __restrict__ feat,
                     const float* __restrict__ centers,
                     const int* __restrict__ labels,
                     const float* __restrict__ halfc2,
                     float* __restrict__ out) {
    // 4 waves x (64 rows x 32 floats) = 32 KB; reused for the cross-wave reduce.
    __shared__ float smem[NWAVES * ROWS_PB * DC];

    const int tid  = threadIdx.x;
    const int w    = tid >> 6;      // wave id 0..3 (depth slice)
    const int t    = tid & 63;      // lane id == row within block
    const int row0 = blockIdx.x * ROWS_PB;

    // wave-private tile in float4 units; XOR-swizzled:
    //   slot = r*8 + (j4 ^ (r&7)) holds row r, float4-col j4
    float4* tile4 = reinterpret_cast<float4*>(smem) + w * (ROWS_PB * DC / 4);

    const float4* fb = reinterpret_cast<const float4*>(feat)
                     + (size_t)row0 * (DIM / 4) + w * (WSLICE / 4);

    float acc[NCLS];
#pragma unroll
    for (int c = 0; c < NCLS; ++c) acc[c] = 0.f;

    const int xr = t & 7;           // readback xor key for lane t (row t)

#pragma unroll 1
    for (int s = 0; s < NSTAGE; ++s) {
        __syncthreads();            // prior stage fully consumed before overwrite
        // 8 DMA issues: issue k deposits at (tile4 + k*64) + lane*16 = slot k*64+t.
        // Lane's global source is the float4 belonging in that swizzled slot.
#pragma unroll
        for (int k = 0; k < 8; ++k) {
            int slot = k * 64 + t;
            int r    = slot >> 3;
            int j4   = (slot & 7) ^ (r & 7);
            const float4* gp = fb + (size_t)r * (DIM / 4) + s * (DC / 4) + j4;
            __builtin_amdgcn_global_load_lds((glb_u32_t*)gp,
                                             (lds_u32_t*)(tile4 + k * 64),
                                             16, 0, 0);
        }
        __syncthreads();            // DMA complete (barrier drains vmcnt)

        // Pull row t's 32 floats into registers once (8 batched ds_read_b128),
        // then sweep classes. Live set: f[8]=32 + acc[21] + partials ≈ 60 VGPR.
        float4 f[8];
#pragma unroll
        for (int j = 0; j < 8; ++j)
            f[j] = tile4[t * 8 + (j ^ xr)];

        const float* cbase = centers + w * WSLICE + s * DC;
#pragma unroll
        for (int c = 0; c < NCLS; ++c) {
            const float* cp = cbase + c * DIM;   // wave-uniform -> s_load
            float p0 = 0.f, p1 = 0.f;            // 2 chains: dep path 16x4=64cy < issue
#pragma unroll
            for (int j = 0; j < 8; j += 2) {
                p0 = fmaf(f[j].x,     cp[4*j + 0],
                      fmaf(f[j].y,   cp[4*j + 1],
                       fmaf(f[j].z,  cp[4*j + 2],
                        fmaf(f[j].w, cp[4*j + 3], p0))));
                p1 = fmaf(f[j+1].x,   cp[4*j + 4],
                      fmaf(f[j+1].y,  cp[4*j + 5],
                       fmaf(f[j+1].z, cp[4*j + 6],
                        fmaf(f[j+1].w, cp[4*j + 7], p1))));
            }
            acc[c] += p0 + p1;
        }
    }

    // cross-wave reduce: overlay smem with red[w][t][c], stride REDS=23
    __syncthreads();
#pragma unroll
    for (int c = 0; c < NCLS; ++c)
        smem[(w * ROWS_PB + t) * REDS + c] = acc[c];
    __syncthreads();

    if (w == 0) {
        const int lab = labels[row0 + t];
        float pos = 0.f, neg = FLT_MAX;
#pragma unroll
        for (int c = 0; c < NCLS; ++c) {
            float dot = smem[(0 * ROWS_PB + t) * REDS + c]
                      + smem[(1 * ROWS_PB + t) * REDS + c]
                      + smem[(2 * ROWS_PB + t) * REDS + c]
                      + smem[(3 * ROWS_PB + t) * REDS + c];
            float e = halfc2[c] - dot;               // ||f||^2 cancels in pos-neg
            pos = (c == lab) ? e : pos;
            neg = (c == lab) ? neg : fminf(neg, e);
        }
        float vv = fmaxf(pos + MARGIN_V - neg, 0.f);
#pragma unroll
        for (int off = 32; off > 0; off >>= 1)
            vv += __shfl_down(vv, off, 64);
        if (t == 0) atomicAdd(out, vv * (1.0f / 65536.f));
    }
}

extern "C" void kernel_launch(void* const* d_in, const int* in_sizes, int n_in,
                              void* d_out, int out_size, void* d_ws, size_t ws_size,
                              hipStream_t stream) {
    const float* feat    = (const float*)d_in[0];   // (65536, 512) fp32
    const float* centers = (const float*)d_in[1];   // (21, 512) fp32
    const int*   labels  = (const int*)d_in[2];     // (65536,)
    float* out    = (float*)d_out;                  // scalar loss
    float* halfc2 = (float*)d_ws;                   // 21 floats scratch

    center_norm_kernel<<<NCLS, 64, 0, stream>>>(centers, halfc2, out);

    const int nblocks = 65536 / ROWS_PB;            // 1024 blocks x 256 threads
    tcl_main_kernel<<<nblocks, 256, 0, stream>>>(feat, centers, labels, halfc2, out);
}

// Round 5
// 260.036 us; speedup vs baseline: 1.6018x; 1.0646x over previous
//
#include <hip/hip_runtime.h>
#include <float.h>
#include <stdint.h>

#define DIM      512
#define NCLS     21
#define MARGIN_V 5.0f
#define ROWS_PB  64              // rows per block; lane t of every wave owns row t
#define NWAVES   4               // waves per block, each owns a 128-float depth slice
#define WSLICE   (DIM / NWAVES)  // 128
#define DC       16              // floats staged per stage per wave (per buffer)
#define NSTAGE   (WSLICE / DC)   // 8
#define TILEF4   (ROWS_PB * DC / 4)   // 256 float4 per buffer
#define REDS     23              // padded stride for cross-wave reduce

typedef __attribute__((address_space(3))) uint32_t       lds_u32_t;
typedef const __attribute__((address_space(1))) uint32_t glb_u32_t;

// Kernel 1: halfc2[c] = 0.5*||centers[c]||^2 -> d_ws ; block 0 also zeroes d_out
__global__ __launch_bounds__(64)
void center_norm_kernel(const float* __restrict__ centers,
                        float* __restrict__ halfc2,
                        float* __restrict__ out) {
    const int c = blockIdx.x;
    const int t = threadIdx.x;
    if (c == 0 && t == 0) out[0] = 0.f;     // same-stream order replaces memset
    float s = 0.f;
#pragma unroll
    for (int i = 0; i < DIM / 64; ++i) {
        float v = centers[c * DIM + i * 64 + t];
        s = fmaf(v, v, s);
    }
#pragma unroll
    for (int off = 32; off > 0; off >>= 1)
        s += __shfl_down(s, off, 64);
    if (t == 0) halfc2[c] = 0.5f * s;
}

// Kernel 2: 64 rows/block, depth split across 4 waves; DOUBLE-BUFFERED
// global->LDS DMA (wave-private tiles). The barrier's vmcnt(0) drain waits on
// a DMA issued one compute-phase (~700 cyc) earlier -> latency hidden.
// Compute: single chained fmaf into acc[c] (round-1 shape) to keep VGPR<=~96
// (round 4's 21x2 partial chains made the compiler balloon to 180 VGPR ->
// 2 waves/SIMD -> latency-bound at 10% occupancy).
__global__ __launch_bounds__(256)
void tcl_main_kernel(const float* __restrict__ feat,
                     const float* __restrict__ centers,
                     const int* __restrict__ labels,
                     const float* __restrict__ halfc2,
                     float* __restrict__ out) {
    // 4 waves x 2 buffers x (64 rows x 16 floats) = 32 KB; reused for reduce.
    __shared__ float smem[NWAVES * 2 * ROWS_PB * DC];

    const int tid  = threadIdx.x;
    const int w    = tid >> 6;      // wave id 0..3 (depth slice)
    const int t    = tid & 63;      // lane id == row within block
    const int row0 = blockIdx.x * ROWS_PB;

    float4* bufs[2];
    bufs[0] = reinterpret_cast<float4*>(smem) + (w * 2 + 0) * TILEF4;
    bufs[1] = reinterpret_cast<float4*>(smem) + (w * 2 + 1) * TILEF4;

    const float4* fb = reinterpret_cast<const float4*>(feat)
                     + (size_t)row0 * (DIM / 4) + w * (WSLICE / 4);

    // Per-lane DMA source pointers (stage 0). Issue k deposits at slot k*64+t;
    // slot holds row r=slot>>2, col j4=(slot&3)^(r&3) (2-bit XOR swizzle).
    // Each 4-lane group covers one row's 64 B permuted -> fully coalesced.
    const float4* gp[4];
#pragma unroll
    for (int k = 0; k < 4; ++k) {
        int slot = k * 64 + t;
        int r    = slot >> 2;
        int j4   = (slot & 3) ^ (r & 3);
        gp[k] = fb + (size_t)r * (DIM / 4) + j4;
    }

    float acc[NCLS];
#pragma unroll
    for (int c = 0; c < NCLS; ++c) acc[c] = 0.f;

    const int xr = t & 3;           // readback xor key for lane t (row t)

    // prologue: stage 0 -> buf0
#pragma unroll
    for (int k = 0; k < 4; ++k)
        __builtin_amdgcn_global_load_lds((glb_u32_t*)gp[k],
                                         (lds_u32_t*)(bufs[0] + k * 64),
                                         16, 0, 0);

#pragma unroll 1
    for (int s = 0; s < NSTAGE; ++s) {
        __syncthreads();            // drains own vmcnt(0): DMA(s) complete

        if (s + 1 < NSTAGE) {       // issue next stage now; waited one phase later
            float4* nb = bufs[(s + 1) & 1];
#pragma unroll
            for (int k = 0; k < 4; ++k)
                __builtin_amdgcn_global_load_lds((glb_u32_t*)(gp[k] + (s + 1) * (DC / 4)),
                                                 (lds_u32_t*)(nb + k * 64),
                                                 16, 0, 0);
        }

        // row t's 16 floats (4 ds_read_b128), then 21 chained dot-accumulates
        const float4* tb = bufs[s & 1];
        float4 f0 = tb[t * 4 + (0 ^ xr)];
        float4 f1 = tb[t * 4 + (1 ^ xr)];
        float4 f2 = tb[t * 4 + (2 ^ xr)];
        float4 f3 = tb[t * 4 + (3 ^ xr)];

        const float* cp0 = centers + w * WSLICE + s * DC;
#pragma unroll
        for (int c = 0; c < NCLS; ++c) {
            const float* cp = cp0 + c * DIM;     // wave-uniform -> s_load
            acc[c] = fmaf(f0.x, cp[0],
                      fmaf(f0.y, cp[1],
                       fmaf(f0.z, cp[2],
                        fmaf(f0.w, cp[3],
                         fmaf(f1.x, cp[4],
                          fmaf(f1.y, cp[5],
                           fmaf(f1.z, cp[6],
                            fmaf(f1.w, cp[7],
                             fmaf(f2.x, cp[8],
                              fmaf(f2.y, cp[9],
                               fmaf(f2.z, cp[10],
                                fmaf(f2.w, cp[11],
                                 fmaf(f3.x, cp[12],
                                  fmaf(f3.y, cp[13],
                                   fmaf(f3.z, cp[14],
                                    fmaf(f3.w, cp[15], acc[c]))))))))))))))));
        }
    }

    // cross-wave reduce: overlay smem with red[w][t][c], stride REDS=23
    __syncthreads();
#pragma unroll
    for (int c = 0; c < NCLS; ++c)
        smem[(w * ROWS_PB + t) * REDS + c] = acc[c];
    __syncthreads();

    if (w == 0) {
        const int lab = labels[row0 + t];
        float pos = 0.f, neg = FLT_MAX;
#pragma unroll
        for (int c = 0; c < NCLS; ++c) {
            float dot = smem[(0 * ROWS_PB + t) * REDS + c]
                      + smem[(1 * ROWS_PB + t) * REDS + c]
                      + smem[(2 * ROWS_PB + t) * REDS + c]
                      + smem[(3 * ROWS_PB + t) * REDS + c];
            float e = halfc2[c] - dot;               // ||f||^2 cancels in pos-neg
            pos = (c == lab) ? e : pos;
            neg = (c == lab) ? neg : fminf(neg, e);
        }
        float vv = fmaxf(pos + MARGIN_V - neg, 0.f);
#pragma unroll
        for (int off = 32; off > 0; off >>= 1)
            vv += __shfl_down(vv, off, 64);
        if (t == 0) atomicAdd(out, vv * (1.0f / 65536.f));
    }
}

extern "C" void kernel_launch(void* const* d_in, const int* in_sizes, int n_in,
                              void* d_out, int out_size, void* d_ws, size_t ws_size,
                              hipStream_t stream) {
    const float* feat    = (const float*)d_in[0];   // (65536, 512) fp32
    const float* centers = (const float*)d_in[1];   // (21, 512) fp32
    const int*   labels  = (const int*)d_in[2];     // (65536,)
    float* out    = (float*)d_out;                  // scalar loss
    float* halfc2 = (float*)d_ws;                   // 21 floats scratch

    center_norm_kernel<<<NCLS, 64, 0, stream>>>(centers, halfc2, out);

    const int nblocks = 65536 / ROWS_PB;            // 1024 blocks x 256 threads
    tcl_main_kernel<<<nblocks, 256, 0, stream>>>(feat, centers, labels, halfc2, out);
}